// Round 2
// baseline (332.992 us; speedup 1.0000x reference)
//
#include <hip/hip_runtime.h>

#define NFEAT 256
#define HID 64
#define NCLASS 40
#define EPB 4096        // edges per k_bin block
#define BCAP 8192       // per-bucket capacity (words / csr entries)

typedef _Float16 half8 __attribute__((ext_vector_type(8)));
typedef float floatx4 __attribute__((ext_vector_type(4)));

__device__ __forceinline__ void gld_lds16(const _Float16* g, _Float16* l) {
    __builtin_amdgcn_global_load_lds(
        (const __attribute__((address_space(1))) void*)g,
        (__attribute__((address_space(3))) void*)l, 16, 0, 0);
}

// ---------- phase 1: bin edges into 512-node buckets + tail blocks convert W to fp16^T ----------
__global__ __launch_bounds__(256) void k_bin(const int* __restrict__ src, const int* __restrict__ dst,
                                             int* __restrict__ bcur, int* __restrict__ bwords,
                                             int nbuckets, int E, int nbin,
                                             const float* __restrict__ W1, const float* __restrict__ W2,
                                             const float* __restrict__ W3, _Float16* __restrict__ Wt16) {
    __shared__ int lcnt[256], loff[256], lcur[256], gbase[256], sc[256];
    __shared__ int sdst[EPB];      // 16 KB
    __shared__ int words[EPB];     // 16 KB
    int t = threadIdx.x;
    if (blockIdx.x >= (unsigned)nbin) {
        // W conversion: wt[col*64 + k] = (fp16) W[k*64 + col]
        int l = blockIdx.x - nbin;
        const float* Ws = (l == 0) ? W1 : (l == 1) ? W2 : W3;
        _Float16* wt = Wt16 + l * 4096;
        for (int i = t; i < 4096; i += 256) {
            int col = i >> 6, k = i & 63;
            wt[i] = (_Float16)Ws[k * HID + col];
        }
        return;
    }
    int base = blockIdx.x * EPB;
    int n = E - base; if (n > EPB) n = EPB;
    lcnt[t] = 0;
    __syncthreads();
    for (int i = t; i < n; i += 256) {
        int d = dst[base + i];
        sdst[i] = d;
        atomicAdd(&lcnt[d >> 9], 1);
    }
    __syncthreads();
    int v = lcnt[t];
    sc[t] = v; __syncthreads();
    for (int o = 1; o < 256; o <<= 1) {
        int add = (t >= o) ? sc[t - o] : 0;
        __syncthreads();
        sc[t] += add;
        __syncthreads();
    }
    int excl = sc[t] - v;
    loff[t] = excl; lcur[t] = excl;
    __syncthreads();
    for (int i = t; i < n; i += 256) {
        int d = sdst[i], s = src[base + i];
        int b = d >> 9;
        int p = atomicAdd(&lcur[b], 1);
        words[p] = s | ((d & 511) << 17);     // s < 2^17
    }
    __syncthreads();
    if (t < nbuckets) {
        int c = lcnt[t];
        gbase[t] = c > 0 ? atomicAdd(&bcur[t], c) : 0;
    }
    __syncthreads();
    int lane = t & 63, wv = t >> 6;
    for (int b = wv; b < nbuckets; b += 4) {
        int o = loff[b], c = lcnt[b], gb = gbase[b];
        int* dstp = bwords + (size_t)b * BCAP;
        for (int i = lane; i < c; i += 64) {
            int gp = gb + i;
            if (gp < BCAP) dstp[gp] = words[o + i];
        }
    }
}

// ---------- phase 2: per-bucket CSR build + pk/dinv ----------
__global__ __launch_bounds__(256) void k_csr(const int* __restrict__ bcur, const int* __restrict__ bwords,
                                             int* __restrict__ csr, unsigned* __restrict__ pk,
                                             float* __restrict__ dinv, int N) {
    __shared__ int cnt[512], cur[512], sc[256];
    __shared__ int lcsr[BCAP];     // 32 KB
    int t = threadIdx.x;
    int b = blockIdx.x;
    int nodebase = b << 9;
    int nb = bcur[b]; if (nb > BCAP) nb = BCAP;
    cnt[t] = 0; cnt[t + 256] = 0;
    __syncthreads();
    const int* wp = bwords + (size_t)b * BCAP;
    for (int i = t; i < nb; i += 256)
        atomicAdd(&cnt[wp[i] >> 17], 1);
    __syncthreads();
    int v0 = cnt[2 * t], v1 = cnt[2 * t + 1];
    int p = v0 + v1;
    sc[t] = p; __syncthreads();
    for (int o = 1; o < 256; o <<= 1) {
        int add = (t >= o) ? sc[t - o] : 0;
        __syncthreads();
        sc[t] += add;
        __syncthreads();
    }
    int e = sc[t] - p;
    cur[2 * t] = e; cur[2 * t + 1] = e + v0;
    #pragma unroll
    for (int j = 0; j < 2; ++j) {
        int node = nodebase + 2 * t + j;
        if (node < N) {
            int c = cnt[2 * t + j]; if (c > 2047) c = 2047;
            pk[node] = (unsigned)(b * BCAP + cur[2 * t + j]) | ((unsigned)c << 21);
            dinv[node] = rsqrtf((float)c + 1.0f);
        }
    }
    __syncthreads();
    for (int i = t; i < nb; i += 256) {
        int w = wp[i];
        int pos = atomicAdd(&cur[w >> 17], 1);
        lcsr[pos] = w & 0x1FFFF;
    }
    __syncthreads();
    int* cp = csr + (size_t)b * BCAP;
    for (int i = t; i < nb; i += 256) cp[i] = lcsr[i];
}

// ---------- h0 = relu(x @ Wx + bx) : MFMA fp16, 512-thr blocks ----------
__global__ __launch_bounds__(512) void k_gemm_in(const float* __restrict__ x, const float* __restrict__ Wx,
                                                 const float* __restrict__ bx, _Float16* __restrict__ h0, int N) {
    __shared__ _Float16 Wt[64][264];   // [col][k]
    int t = threadIdx.x;
    {
        int c = t & 63, k0 = (t >> 6) * 32;
        for (int k = k0; k < k0 + 32; ++k)
            Wt[c][k] = (_Float16)Wx[k * HID + c];
    }
    __syncthreads();
    int lane = t & 63, lg = lane >> 4, ln = lane & 15;
    int wid = (blockIdx.x * 512 + t) >> 6;
    int nw = (gridDim.x * 512) >> 6;
    float bb[4];
    #pragma unroll
    for (int g = 0; g < 4; ++g) bb[g] = bx[g * 16 + ln];
    int ntiles = N >> 4;
    for (int tile = wid; tile < ntiles; tile += nw) {
        int row0 = tile << 4;
        const float* xr = x + (size_t)(row0 + ln) * NFEAT + lg * 8;
        float4 av[16];
        #pragma unroll
        for (int ks = 0; ks < 8; ++ks) {
            av[2 * ks]     = *(const float4*)(xr + ks * 32);
            av[2 * ks + 1] = *(const float4*)(xr + ks * 32 + 4);
        }
        floatx4 acc[4] = {{0.f,0.f,0.f,0.f},{0.f,0.f,0.f,0.f},{0.f,0.f,0.f,0.f},{0.f,0.f,0.f,0.f}};
        #pragma unroll
        for (int ks = 0; ks < 8; ++ks) {
            float4 a0 = av[2 * ks], a1 = av[2 * ks + 1];
            half8 a;
            a[0]=(_Float16)a0.x; a[1]=(_Float16)a0.y; a[2]=(_Float16)a0.z; a[3]=(_Float16)a0.w;
            a[4]=(_Float16)a1.x; a[5]=(_Float16)a1.y; a[6]=(_Float16)a1.z; a[7]=(_Float16)a1.w;
            #pragma unroll
            for (int g = 0; g < 4; ++g) {
                half8 b = *(const half8*)&Wt[g * 16 + ln][ks * 32 + lg * 8];
                acc[g] = __builtin_amdgcn_mfma_f32_16x16x32_f16(a, b, acc[g], 0, 0, 0);
            }
        }
        #pragma unroll
        for (int g = 0; g < 4; ++g) {
            #pragma unroll
            for (int r = 0; r < 4; ++r) {
                int row = row0 + lg * 4 + r;
                h0[(size_t)row * HID + g * 16 + ln] = (_Float16)fmaxf(acc[g][r] + bb[g], 0.f);
            }
        }
    }
}

// ---------- fused GCN layer ----------
// block = 256 thr = 4 waves = 32 nodes; wave = 8 subgroups x 8 lanes (sg owns node, f8 owns 16B
// feature seg). Neighbor rows staged into LDS via global_load_lds DMA (8 rows x 8 sg = 8 KB/wave
// in flight -> BW-bound instead of latency-bound). WRN=1: compute+cache per-edge norm; WRN=0: load it.
template<int WRN>
__global__ __launch_bounds__(256) void k_layer(const _Float16* __restrict__ Ph, const int* __restrict__ csr,
                                               const unsigned* __restrict__ pk, const float* __restrict__ dinv,
                                               const _Float16* __restrict__ Wt, const float* __restrict__ b,
                                               float* __restrict__ normf,
                                               _Float16* __restrict__ Lout, int N) {
    __shared__ _Float16 stage[4][8][8][64];   // [wave][slot][sg][feat] = 32 KB
    __shared__ _Float16 z[32][72];            // aggregated features
    _Float16 (*ot)[72] = (_Float16 (*)[72])&stage[0][0][0][0];   // overlay after barrier
    int t = threadIdx.x;
    int lane = t & 63, wv = t >> 6;
    int sg = lane >> 3, f8 = lane & 7;
    int lg = lane >> 4, ln = lane & 15;
    int nb = blockIdx.x << 5;
    int node = nb + wv * 8 + sg;
    int nodec = node < N ? node : (N - 1);
    // B fragment from pre-converted fp16 W^T: 2 x half8 loads
    int col = wv * 16 + ln;
    half8 bf0 = *(const half8*)(Wt + col * 64 + lg * 8);
    half8 bf1 = *(const half8*)(Wt + col * 64 + 32 + lg * 8);
    float bb = b[col];

    unsigned pkv = (node < N) ? pk[node] : 0u;
    int off = (int)(pkv & 0x1FFFFFu);
    int c = (int)(pkv >> 21);
    float dd = (node < N) ? dinv[node] : 0.f;
    float acc[8];
    {
        half8 self = *(const half8*)(Ph + (size_t)nodec * HID + f8 * 8);
        float dd2 = dd * dd;
        #pragma unroll
        for (int j = 0; j < 8; ++j) acc[j] = (float)self[j] * dd2;
    }
    // wave-uniform chunk count = max degree over the wave's 8 subgroups
    int cm = c;
    cm = max(cm, __shfl_xor(cm, 8));
    cm = max(cm, __shfl_xor(cm, 16));
    cm = max(cm, __shfl_xor(cm, 32));
    for (int jj = 0; jj < cm; jj += 8) {
        int e = jj + f8;
        bool ok = e < c;
        int s = nodec;
        float nm = 0.f;
        if (ok) {
            s = csr[off + e];
            if (WRN) {
                nm = dinv[s] * dd;
                normf[off + e] = nm;
            } else {
                nm = normf[off + e];
            }
        }
        // stage 8 neighbor rows per subgroup via DMA (dest: linear lane*16B)
        #pragma unroll
        for (int j = 0; j < 8; ++j) {
            int ss = __shfl(s, j, 8);
            gld_lds16(Ph + (size_t)ss * HID + f8 * 8, &stage[wv][j][0][0]);
        }
        asm volatile("s_waitcnt vmcnt(0)" ::: "memory");
        #pragma unroll
        for (int j = 0; j < 8; ++j) {
            float nn = __shfl(nm, j, 8);
            half8 v = *(const half8*)&stage[wv][j][sg][f8 * 8];
            #pragma unroll
            for (int q = 0; q < 8; ++q) acc[q] = fmaf((float)v[q], nn, acc[q]);
        }
    }
    {
        half8 zv;
        #pragma unroll
        for (int j = 0; j < 8; ++j) zv[j] = (_Float16)acc[j];
        *(half8*)&z[wv * 8 + sg][f8 * 8] = zv;
    }
    __syncthreads();
    // MFMA: two 16-row tiles; out[rows][wv*16 .. wv*16+15] = z @ W
    floatx4 acc0 = {0.f, 0.f, 0.f, 0.f}, acc1 = {0.f, 0.f, 0.f, 0.f};
    {
        half8 a0 = *(const half8*)&z[ln][lg * 8];
        half8 a1 = *(const half8*)&z[16 + ln][lg * 8];
        acc0 = __builtin_amdgcn_mfma_f32_16x16x32_f16(a0, bf0, acc0, 0, 0, 0);
        acc1 = __builtin_amdgcn_mfma_f32_16x16x32_f16(a1, bf0, acc1, 0, 0, 0);
        a0 = *(const half8*)&z[ln][32 + lg * 8];
        a1 = *(const half8*)&z[16 + ln][32 + lg * 8];
        acc0 = __builtin_amdgcn_mfma_f32_16x16x32_f16(a0, bf1, acc0, 0, 0, 0);
        acc1 = __builtin_amdgcn_mfma_f32_16x16x32_f16(a1, bf1, acc1, 0, 0, 0);
    }
    #pragma unroll
    for (int r = 0; r < 4; ++r) {
        ot[lg * 4 + r][wv * 16 + ln] = (_Float16)(acc0[r] + bb);
        ot[16 + lg * 4 + r][wv * 16 + ln] = (_Float16)(acc1[r] + bb);
    }
    __syncthreads();
    // coalesced store of the 32x64 fp16 tile
    {
        int row = t >> 3, c8 = t & 7;
        int onode = nb + row;
        if (onode < N)
            *(half8*)(Lout + (size_t)onode * HID + c8 * 8) = *(const half8*)&ot[row][c8 * 8];
    }
}

// ---------- out = relu(((L1+L2+L3)/3) @ Wz + bz) ----------
__global__ __launch_bounds__(256) void k_gemm_out(const _Float16* __restrict__ L1, const _Float16* __restrict__ L2,
                                                  const _Float16* __restrict__ L3, const float* __restrict__ Wz,
                                                  const float* __restrict__ bz, float* __restrict__ outp, int N) {
    int t = threadIdx.x;
    int lane = t & 63, lg = lane >> 4, ln = lane & 15;
    int wid = (blockIdx.x * 256 + t) >> 6;
    int nw = (gridDim.x * 256) >> 6;
    half8 b[2][3];
    float bb[3];
    #pragma unroll
    for (int g = 0; g < 3; ++g) {
        int col = g * 16 + ln;
        bb[g] = (col < NCLASS) ? bz[col] : 0.f;
        #pragma unroll
        for (int ks = 0; ks < 2; ++ks)
            #pragma unroll
            for (int j = 0; j < 8; ++j)
                b[ks][g][j] = (col < NCLASS) ? (_Float16)(Wz[(ks * 32 + lg * 8 + j) * NCLASS + col] * (1.f / 3.f)) : (_Float16)0.f;
    }
    int ntiles = N >> 4;
    for (int tile = wid; tile < ntiles; tile += nw) {
        int row0 = tile << 4;
        size_t rb = (size_t)(row0 + ln) * HID + lg * 8;
        floatx4 acc[3] = {{0.f,0.f,0.f,0.f},{0.f,0.f,0.f,0.f},{0.f,0.f,0.f,0.f}};
        #pragma unroll
        for (int ks = 0; ks < 2; ++ks) {
            half8 a1 = *(const half8*)(L1 + rb + ks * 32);
            half8 a2 = *(const half8*)(L2 + rb + ks * 32);
            half8 a3 = *(const half8*)(L3 + rb + ks * 32);
            half8 a;
            #pragma unroll
            for (int j = 0; j < 8; ++j)
                a[j] = (_Float16)((float)a1[j] + (float)a2[j] + (float)a3[j]);
            #pragma unroll
            for (int g = 0; g < 3; ++g)
                acc[g] = __builtin_amdgcn_mfma_f32_16x16x32_f16(a, b[ks][g], acc[g], 0, 0, 0);
        }
        #pragma unroll
        for (int g = 0; g < 3; ++g) {
            int col = g * 16 + ln;
            if (col < NCLASS) {
                #pragma unroll
                for (int r = 0; r < 4; ++r)
                    outp[(size_t)(row0 + lg * 4 + r) * NCLASS + col] = fmaxf(acc[g][r] + bb[g], 0.f);
            }
        }
    }
}

extern "C" void kernel_launch(void* const* d_in, const int* in_sizes, int n_in,
                              void* d_out, int out_size, void* d_ws, size_t ws_size,
                              hipStream_t stream) {
    const float* x  = (const float*)d_in[0];
    const int*   ei = (const int*)d_in[1];
    const float* Wx = (const float*)d_in[2];
    const float* bx = (const float*)d_in[3];
    const float* W1 = (const float*)d_in[4];
    const float* b1 = (const float*)d_in[5];
    const float* W2 = (const float*)d_in[6];
    const float* b2 = (const float*)d_in[7];
    const float* W3 = (const float*)d_in[8];
    const float* b3 = (const float*)d_in[9];
    const float* Wz = (const float*)d_in[10];
    const float* bz = (const float*)d_in[11];
    float* out = (float*)d_out;

    int N = in_sizes[0] / NFEAT;
    int E = in_sizes[1] / 2;
    const int* src = ei;
    const int* dst = ei + E;
    int nbuckets = (N + 511) >> 9;   // 196 for N=100000 (<=256)

    size_t nh = (size_t)N * HID;
    size_t Npad = ((size_t)N + 7) / 8 * 8;
    // 4B-unit layout: bcur[256] | dinv | pk | H0 | L1 | L2 | L3 | bwords | csr | Wt16 | normf
    int*      bcur = (int*)d_ws;
    float*    dinv = (float*)d_ws + 256;
    unsigned* pk   = (unsigned*)(dinv + Npad);
    _Float16* H0   = (_Float16*)(pk + Npad);
    _Float16* L1   = H0 + nh;
    _Float16* L2   = L1 + nh;
    _Float16* L3   = L2 + nh;
    int*      bwords = (int*)(L3 + nh);
    int*      csr  = bwords + (size_t)nbuckets * BCAP;
    _Float16* Wt16 = (_Float16*)(csr + (size_t)nbuckets * BCAP);
    float*    normf = (float*)(Wt16 + 3 * 4096);

    int nbin = (E + EPB - 1) / EPB;
    hipMemsetAsync(bcur, 0, 256 * sizeof(int), stream);
    k_bin<<<nbin + 3, 256, 0, stream>>>(src, dst, bcur, bwords, nbuckets, E, nbin, W1, W2, W3, Wt16);
    k_csr<<<nbuckets, 256, 0, stream>>>(bcur, bwords, csr, pk, dinv, N);

    k_gemm_in<<<256, 512, 0, stream>>>(x, Wx, bx, H0, N);

    int layer_blocks = (N + 31) / 32;
    k_layer<1><<<layer_blocks, 256, 0, stream>>>(H0, csr, pk, dinv, Wt16,          b1, normf, L1, N);
    k_layer<0><<<layer_blocks, 256, 0, stream>>>(L1, csr, pk, dinv, Wt16 + 4096,   b2, normf, L2, N);
    k_layer<0><<<layer_blocks, 256, 0, stream>>>(L2, csr, pk, dinv, Wt16 + 8192,   b3, normf, L3, N);

    k_gemm_out<<<512, 256, 0, stream>>>(L1, L2, L3, Wz, bz, out, N);
}

// Round 4
// 285.223 us; speedup vs baseline: 1.1675x; 1.1675x over previous
//
#include <hip/hip_runtime.h>

#define NFEAT 256
#define HID 64
#define NCLASS 40
#define EPB 4096        // edges per k_bin block
#define BCAP 8192       // per-bucket capacity (words / csr entries)

typedef _Float16 half8 __attribute__((ext_vector_type(8)));
typedef float floatx4 __attribute__((ext_vector_type(4)));

struct BinSM {
    int lcnt[256], loff[256], lcur[256], gbase[256], sc[256];
    int sdst[EPB];
    int words[EPB];
};

// ---------- fused preprocessing: edge binning + W1..3 fp16^T convert + h0 GEMM ----------
// blocks [0, nbin): bin edges into 512-node buckets
// blocks [nbin, nbin+3): convert W_l to fp16 transposed
// blocks [nbin+3, nbin+3+ngemm): h0 = relu(x @ Wx + bx) via MFMA
__global__ __launch_bounds__(256) void k_pre(const int* __restrict__ src, const int* __restrict__ dst,
                                             int* __restrict__ bcur, int* __restrict__ bwords,
                                             int nbuckets, int E, int nbin,
                                             const float* __restrict__ W1, const float* __restrict__ W2,
                                             const float* __restrict__ W3, _Float16* __restrict__ Wt16,
                                             const float* __restrict__ x, const float* __restrict__ Wx,
                                             const float* __restrict__ bx, _Float16* __restrict__ h0,
                                             int N, int ngemm) {
    __shared__ __align__(16) char smraw[sizeof(BinSM)];   // 37.9 KB, overlaid views
    int t = threadIdx.x;
    int bid = blockIdx.x;

    if (bid >= nbin && bid < nbin + 3) {
        // W conversion: wt[col*64 + k] = (fp16) W[k*64 + col]
        int l = bid - nbin;
        const float* Ws = (l == 0) ? W1 : (l == 1) ? W2 : W3;
        _Float16* wt = Wt16 + l * 4096;
        for (int i = t; i < 4096; i += 256) {
            int col = i >> 6, k = i & 63;
            wt[i] = (_Float16)Ws[k * HID + col];
        }
        return;
    }

    if (bid >= nbin + 3) {
        // ---- h0 GEMM part ----
        _Float16 (*Wt)[264] = (_Float16 (*)[264])smraw;   // 64 x 264 fp16 = 33.8 KB
        {
            int c = t & 63, k0 = (t >> 6) * 64;
            for (int k = k0; k < k0 + 64; ++k)
                Wt[c][k] = (_Float16)Wx[k * HID + c];
        }
        __syncthreads();
        int lane = t & 63, wv = t >> 6;
        int lg = lane >> 4, ln = lane & 15;
        int gb = bid - nbin - 3;
        int wid = gb * 4 + wv;
        int nw = ngemm * 4;
        float bb[4];
        #pragma unroll
        for (int g = 0; g < 4; ++g) bb[g] = bx[g * 16 + ln];
        int ntiles = N >> 4;
        for (int tile = wid; tile < ntiles; tile += nw) {
            int row0 = tile << 4;
            const float* xr = x + (size_t)(row0 + ln) * NFEAT + lg * 8;
            float4 av[16];
            #pragma unroll
            for (int ks = 0; ks < 8; ++ks) {
                av[2 * ks]     = *(const float4*)(xr + ks * 32);
                av[2 * ks + 1] = *(const float4*)(xr + ks * 32 + 4);
            }
            floatx4 acc[4] = {{0.f,0.f,0.f,0.f},{0.f,0.f,0.f,0.f},{0.f,0.f,0.f,0.f},{0.f,0.f,0.f,0.f}};
            #pragma unroll
            for (int ks = 0; ks < 8; ++ks) {
                float4 a0 = av[2 * ks], a1 = av[2 * ks + 1];
                half8 a;
                a[0]=(_Float16)a0.x; a[1]=(_Float16)a0.y; a[2]=(_Float16)a0.z; a[3]=(_Float16)a0.w;
                a[4]=(_Float16)a1.x; a[5]=(_Float16)a1.y; a[6]=(_Float16)a1.z; a[7]=(_Float16)a1.w;
                #pragma unroll
                for (int g = 0; g < 4; ++g) {
                    half8 b = *(const half8*)&Wt[g * 16 + ln][ks * 32 + lg * 8];
                    acc[g] = __builtin_amdgcn_mfma_f32_16x16x32_f16(a, b, acc[g], 0, 0, 0);
                }
            }
            #pragma unroll
            for (int g = 0; g < 4; ++g) {
                #pragma unroll
                for (int r = 0; r < 4; ++r) {
                    int row = row0 + lg * 4 + r;
                    h0[(size_t)row * HID + g * 16 + ln] = (_Float16)fmaxf(acc[g][r] + bb[g], 0.f);
                }
            }
        }
        return;
    }

    // ---- binning part ----
    BinSM* sm = (BinSM*)smraw;
    int base = bid * EPB;
    int n = E - base; if (n > EPB) n = EPB;
    sm->lcnt[t] = 0;
    __syncthreads();
    for (int i = t; i < n; i += 256) {
        int d = dst[base + i];
        sm->sdst[i] = d;
        atomicAdd(&sm->lcnt[d >> 9], 1);
    }
    __syncthreads();
    int v = sm->lcnt[t];
    sm->sc[t] = v; __syncthreads();
    for (int o = 1; o < 256; o <<= 1) {
        int add = (t >= o) ? sm->sc[t - o] : 0;
        __syncthreads();
        sm->sc[t] += add;
        __syncthreads();
    }
    int excl = sm->sc[t] - v;
    sm->loff[t] = excl; sm->lcur[t] = excl;
    __syncthreads();
    for (int i = t; i < n; i += 256) {
        int d = sm->sdst[i], s = src[base + i];
        int b = d >> 9;
        int p = atomicAdd(&sm->lcur[b], 1);
        sm->words[p] = s | ((d & 511) << 17);     // s < 2^17
    }
    __syncthreads();
    if (t < nbuckets) {
        int c = sm->lcnt[t];
        sm->gbase[t] = c > 0 ? atomicAdd(&bcur[t], c) : 0;
    }
    __syncthreads();
    int lane = t & 63, wv = t >> 6;
    for (int b = wv; b < nbuckets; b += 4) {
        int o = sm->loff[b], c = sm->lcnt[b], gb = sm->gbase[b];
        int* dstp = bwords + (size_t)b * BCAP;
        for (int i = lane; i < c; i += 64) {
            int gp = gb + i;
            if (gp < BCAP) dstp[gp] = sm->words[o + i];
        }
    }
}

// ---------- phase 2: per-bucket CSR build + pk/dinv ----------
__global__ __launch_bounds__(256) void k_csr(const int* __restrict__ bcur, const int* __restrict__ bwords,
                                             int* __restrict__ csr, unsigned* __restrict__ pk,
                                             float* __restrict__ dinv, int N) {
    __shared__ int cnt[512], cur[512], sc[256];
    __shared__ int lcsr[BCAP];     // 32 KB
    int t = threadIdx.x;
    int b = blockIdx.x;
    int nodebase = b << 9;
    int nb = bcur[b]; if (nb > BCAP) nb = BCAP;
    cnt[t] = 0; cnt[t + 256] = 0;
    __syncthreads();
    const int* wp = bwords + (size_t)b * BCAP;
    for (int i = t; i < nb; i += 256)
        atomicAdd(&cnt[wp[i] >> 17], 1);
    __syncthreads();
    int v0 = cnt[2 * t], v1 = cnt[2 * t + 1];
    int p = v0 + v1;
    sc[t] = p; __syncthreads();
    for (int o = 1; o < 256; o <<= 1) {
        int add = (t >= o) ? sc[t - o] : 0;
        __syncthreads();
        sc[t] += add;
        __syncthreads();
    }
    int e = sc[t] - p;
    cur[2 * t] = e; cur[2 * t + 1] = e + v0;
    #pragma unroll
    for (int j = 0; j < 2; ++j) {
        int node = nodebase + 2 * t + j;
        if (node < N) {
            int c = cnt[2 * t + j]; if (c > 2047) c = 2047;
            pk[node] = (unsigned)(b * BCAP + cur[2 * t + j]) | ((unsigned)c << 21);
            dinv[node] = rsqrtf((float)c + 1.0f);
        }
    }
    __syncthreads();
    for (int i = t; i < nb; i += 256) {
        int w = wp[i];
        int pos = atomicAdd(&cur[w >> 17], 1);
        lcsr[pos] = w & 0x1FFFF;
    }
    __syncthreads();
    int* cp = csr + (size_t)b * BCAP;
    for (int i = t; i < nb; i += 256) cp[i] = lcsr[i];
}

// ---------- fused GCN layer: z = A·h (gather+self), then out = z@W + b via MFMA ----------
// block = 256 thr = 4 waves = 32 nodes; wave = 8 subgroups x 8 lanes (sg owns node, f8 owns
// 16B feature seg). VGPR gathers (8 rows/chunk in flight); next chunk's csr/norm prefetched
// during consume to hide the serial csr->norm chain. WRN=1: compute+cache norm; WRN=0: load it.
template<int WRN>
__global__ __launch_bounds__(256) void k_layer(const _Float16* __restrict__ Ph, const int* __restrict__ csr,
                                               const unsigned* __restrict__ pk, const float* __restrict__ dinv,
                                               const _Float16* __restrict__ Wt, const float* __restrict__ b,
                                               float* __restrict__ normf,
                                               _Float16* __restrict__ Lout, int N) {
    __shared__ _Float16 z[32][72];     // aggregated features
    __shared__ _Float16 ot[32][72];    // output tile
    int t = threadIdx.x;
    int lane = t & 63, wv = t >> 6;
    int sg = lane >> 3, f8 = lane & 7;
    int lg = lane >> 4, ln = lane & 15;
    int nb = blockIdx.x << 5;
    int node = nb + wv * 8 + sg;
    bool valid = node < N;
    int nodec = valid ? node : (N - 1);
    // B fragment from pre-converted fp16 W^T: 2 x half8 loads
    int col = wv * 16 + ln;
    half8 bf0 = *(const half8*)(Wt + col * 64 + lg * 8);
    half8 bf1 = *(const half8*)(Wt + col * 64 + 32 + lg * 8);
    float bb = b[col];

    unsigned pkv = valid ? pk[node] : 0u;
    int off = (int)(pkv & 0x1FFFFFu);
    int c = (int)(pkv >> 21);
    float dd = valid ? dinv[node] : 0.f;
    const _Float16* pb = Ph + f8 * 8;
    float acc[8];
    {
        half8 self = *(const half8*)(pb + (size_t)nodec * HID);
        float dd2 = dd * dd;
        #pragma unroll
        for (int j = 0; j < 8; ++j) acc[j] = (float)self[j] * dd2;
    }
    // prologue: chunk 0's edge data
    int ecur = f8;
    bool ok = ecur < c;
    int s_cur = ok ? csr[off + ecur] : nodec;
    float nm_cur;
    if (WRN) {
        nm_cur = ok ? dinv[s_cur] * dd : 0.f;
        if (ok) normf[off + ecur] = nm_cur;
    } else {
        nm_cur = ok ? normf[off + ecur] : 0.f;
    }
    for (int jj = 0; jj < c; jj += 8) {
        // prefetch next chunk's csr/norm (latency hidden under consume below)
        int en = jj + 8 + f8;
        bool okn = en < c;
        int s_nxt = okn ? csr[off + en] : nodec;
        float nm_nxt;
        if (WRN) {
            nm_nxt = okn ? dinv[s_nxt] * dd : 0.f;
            if (okn) normf[off + en] = nm_nxt;
        } else {
            nm_nxt = okn ? normf[off + en] : 0.f;
        }
        // consume current chunk: 8 broadcast rows
        #pragma unroll
        for (int j = 0; j < 8; ++j) {
            int ss = __shfl(s_cur, j, 8);
            float nn = __shfl(nm_cur, j, 8);
            half8 v = *(const half8*)(pb + (size_t)ss * HID);
            #pragma unroll
            for (int q = 0; q < 8; ++q) acc[q] = fmaf((float)v[q], nn, acc[q]);
        }
        s_cur = s_nxt; nm_cur = nm_nxt;
    }
    {
        half8 zv;
        #pragma unroll
        for (int j = 0; j < 8; ++j) zv[j] = (_Float16)acc[j];
        *(half8*)&z[wv * 8 + sg][f8 * 8] = zv;
    }
    __syncthreads();
    // MFMA: two 16-row tiles; out[rows][wv*16 .. wv*16+15] = z @ W
    floatx4 acc0 = {0.f, 0.f, 0.f, 0.f}, acc1 = {0.f, 0.f, 0.f, 0.f};
    {
        half8 a0 = *(const half8*)&z[ln][lg * 8];
        half8 a1 = *(const half8*)&z[16 + ln][lg * 8];
        acc0 = __builtin_amdgcn_mfma_f32_16x16x32_f16(a0, bf0, acc0, 0, 0, 0);
        acc1 = __builtin_amdgcn_mfma_f32_16x16x32_f16(a1, bf0, acc1, 0, 0, 0);
        a0 = *(const half8*)&z[ln][32 + lg * 8];
        a1 = *(const half8*)&z[16 + ln][32 + lg * 8];
        acc0 = __builtin_amdgcn_mfma_f32_16x16x32_f16(a0, bf1, acc0, 0, 0, 0);
        acc1 = __builtin_amdgcn_mfma_f32_16x16x32_f16(a1, bf1, acc1, 0, 0, 0);
    }
    #pragma unroll
    for (int r = 0; r < 4; ++r) {
        ot[lg * 4 + r][wv * 16 + ln] = (_Float16)(acc0[r] + bb);
        ot[16 + lg * 4 + r][wv * 16 + ln] = (_Float16)(acc1[r] + bb);
    }
    __syncthreads();
    // coalesced store of the 32x64 fp16 tile
    {
        int row = t >> 3, c8 = t & 7;
        int onode = nb + row;
        if (onode < N)
            *(half8*)(Lout + (size_t)onode * HID + c8 * 8) = *(const half8*)&ot[row][c8 * 8];
    }
}

// ---------- out = relu(((L1+L2+L3)/3) @ Wz + bz) ----------
__global__ __launch_bounds__(256) void k_gemm_out(const _Float16* __restrict__ L1, const _Float16* __restrict__ L2,
                                                  const _Float16* __restrict__ L3, const float* __restrict__ Wz,
                                                  const float* __restrict__ bz, float* __restrict__ outp, int N) {
    int t = threadIdx.x;
    int lane = t & 63, lg = lane >> 4, ln = lane & 15;
    int wid = (blockIdx.x * 256 + t) >> 6;
    int nw = (gridDim.x * 256) >> 6;
    half8 b[2][3];
    float bb[3];
    #pragma unroll
    for (int g = 0; g < 3; ++g) {
        int col = g * 16 + ln;
        bb[g] = (col < NCLASS) ? bz[col] : 0.f;
        #pragma unroll
        for (int ks = 0; ks < 2; ++ks)
            #pragma unroll
            for (int j = 0; j < 8; ++j)
                b[ks][g][j] = (col < NCLASS) ? (_Float16)(Wz[(ks * 32 + lg * 8 + j) * NCLASS + col] * (1.f / 3.f)) : (_Float16)0.f;
    }
    int ntiles = N >> 4;
    for (int tile = wid; tile < ntiles; tile += nw) {
        int row0 = tile << 4;
        size_t rb = (size_t)(row0 + ln) * HID + lg * 8;
        floatx4 acc[3] = {{0.f,0.f,0.f,0.f},{0.f,0.f,0.f,0.f},{0.f,0.f,0.f,0.f}};
        #pragma unroll
        for (int ks = 0; ks < 2; ++ks) {
            half8 a1 = *(const half8*)(L1 + rb + ks * 32);
            half8 a2 = *(const half8*)(L2 + rb + ks * 32);
            half8 a3 = *(const half8*)(L3 + rb + ks * 32);
            half8 a;
            #pragma unroll
            for (int j = 0; j < 8; ++j)
                a[j] = (_Float16)((float)a1[j] + (float)a2[j] + (float)a3[j]);
            #pragma unroll
            for (int g = 0; g < 3; ++g)
                acc[g] = __builtin_amdgcn_mfma_f32_16x16x32_f16(a, b[ks][g], acc[g], 0, 0, 0);
        }
        #pragma unroll
        for (int g = 0; g < 3; ++g) {
            int col = g * 16 + ln;
            if (col < NCLASS) {
                #pragma unroll
                for (int r = 0; r < 4; ++r)
                    outp[(size_t)(row0 + lg * 4 + r) * NCLASS + col] = fmaxf(acc[g][r] + bb[g], 0.f);
            }
        }
    }
}

extern "C" void kernel_launch(void* const* d_in, const int* in_sizes, int n_in,
                              void* d_out, int out_size, void* d_ws, size_t ws_size,
                              hipStream_t stream) {
    const float* x  = (const float*)d_in[0];
    const int*   ei = (const int*)d_in[1];
    const float* Wx = (const float*)d_in[2];
    const float* bx = (const float*)d_in[3];
    const float* W1 = (const float*)d_in[4];
    const float* b1 = (const float*)d_in[5];
    const float* W2 = (const float*)d_in[6];
    const float* b2 = (const float*)d_in[7];
    const float* W3 = (const float*)d_in[8];
    const float* b3 = (const float*)d_in[9];
    const float* Wz = (const float*)d_in[10];
    const float* bz = (const float*)d_in[11];
    float* out = (float*)d_out;

    int N = in_sizes[0] / NFEAT;
    int E = in_sizes[1] / 2;
    const int* src = ei;
    const int* dst = ei + E;
    int nbuckets = (N + 511) >> 9;   // 196 for N=100000 (<=256)

    size_t nh = (size_t)N * HID;
    size_t Npad = ((size_t)N + 7) / 8 * 8;
    // 4B-unit layout: bcur[256] | dinv | pk | H0 | L1 | L2 | L3 | bwords | csr | Wt16 | normf
    int*      bcur = (int*)d_ws;
    float*    dinv = (float*)d_ws + 256;
    unsigned* pk   = (unsigned*)(dinv + Npad);
    _Float16* H0   = (_Float16*)(pk + Npad);
    _Float16* L1   = H0 + nh;
    _Float16* L2   = L1 + nh;
    _Float16* L3   = L2 + nh;
    int*      bwords = (int*)(L3 + nh);
    int*      csr  = bwords + (size_t)nbuckets * BCAP;
    _Float16* Wt16 = (_Float16*)(csr + (size_t)nbuckets * BCAP);
    float*    normf = (float*)(Wt16 + 3 * 4096);

    int nbin = (E + EPB - 1) / EPB;
    int ngemm = 512;
    hipMemsetAsync(bcur, 0, 256 * sizeof(int), stream);
    k_pre<<<nbin + 3 + ngemm, 256, 0, stream>>>(src, dst, bcur, bwords, nbuckets, E, nbin,
                                                W1, W2, W3, Wt16, x, Wx, bx, H0, N, ngemm);
    k_csr<<<nbuckets, 256, 0, stream>>>(bcur, bwords, csr, pk, dinv, N);

    int layer_blocks = (N + 31) / 32;
    k_layer<1><<<layer_blocks, 256, 0, stream>>>(H0, csr, pk, dinv, Wt16,          b1, normf, L1, N);
    k_layer<0><<<layer_blocks, 256, 0, stream>>>(L1, csr, pk, dinv, Wt16 + 4096,   b2, normf, L2, N);
    k_layer<0><<<layer_blocks, 256, 0, stream>>>(L2, csr, pk, dinv, Wt16 + 8192,   b3, normf, L3, N);

    k_gemm_out<<<512, 256, 0, stream>>>(L1, L2, L3, Wz, bz, out, N);
}